// Round 2
// baseline (500.934 us; speedup 1.0000x reference)
//
#include <hip/hip_runtime.h>

#define SEQ 2048
#define DIN 2048
#define NH 16
#define NKVH 4
#define DH 128
#define NQ 2048   /* NH*DH */
#define QSCALE 0.088388347648318447f  /* 1/sqrt(128) */

typedef unsigned short ushort_t;
typedef __attribute__((ext_vector_type(8))) __bf16 bf16x8;
typedef __attribute__((ext_vector_type(8))) unsigned short ushort8;
typedef __attribute__((ext_vector_type(4))) float f32x4;

__device__ __forceinline__ float b2f(ushort_t u){ return __uint_as_float(((unsigned int)u)<<16); }
__device__ __forceinline__ ushort_t f2b(float f){
  unsigned int u = __float_as_uint(f);
  u += 0x7fff + ((u>>16)&1);            // RNE
  return (ushort_t)(u>>16);
}
__device__ __forceinline__ f32x4 mfma16(bf16x8 a, bf16x8 b, f32x4 c){
  return __builtin_amdgcn_mfma_f32_16x16x32_bf16(a, b, c, 0, 0, 0);
}
__device__ __forceinline__ void gload16(const void* g, void* l){
  __builtin_amdgcn_global_load_lds((__attribute__((address_space(1))) void*)(void*)g,
                                   (__attribute__((address_space(3))) void*)l, 16, 0, 0);
}

// ---------------------------------------------------------------- dtype detector
// Reads first 4096 u16 of Wq as bf16. Real bf16 Wq: all |v| <= 1/45. fp32 bit
// stream: mantissa halves are junk bf16 with huge exponents -> any_big fires.
__global__ void detect_bf16(const ushort_t* __restrict__ wq, int* __restrict__ flag){
  __shared__ int any_big;
  if (threadIdx.x==0) any_big = 0;
  __syncthreads();
  int big = 0;
  for (int i=threadIdx.x; i<4096; i+=256){
    float v = b2f(wq[i]);
    if (!(fabsf(v) < 1.0f)) big = 1;    // catches NaN/inf too
  }
  if (big) atomicOr(&any_big, 1);
  __syncthreads();
  if (threadIdx.x==0) flag[0] = any_big ? 0 : 1;   // 0 = fp32 inputs, 1 = bf16 inputs
}

// ---------------------------------------------------------------- GEMM staging
// Stage a [128][32]-element tile into bf16 LDS (rows of 32 elems), from either
// fp32 or bf16 global source. Reg-staged (no global_load_lds: need conversion).
__device__ __forceinline__ void stage_tile(const void* src, int ld, int is_b16,
                                           ushort_t* lds, int tid){
  const int r = tid>>1, c0 = (tid&1)*16;
  ushort8 w0, w1;
  if (is_b16){
    const ushort_t* s = (const ushort_t*)src + (size_t)r*ld + c0;
    w0 = *(const ushort8*)s;
    w1 = *(const ushort8*)(s+8);
  } else {
    const float* s = (const float*)src + (size_t)r*ld + c0;
    f32x4 a0 = *(const f32x4*)(s),   a1 = *(const f32x4*)(s+4);
    f32x4 a2 = *(const f32x4*)(s+8), a3 = *(const f32x4*)(s+12);
    #pragma unroll
    for (int e=0;e<4;e++){
      w0[e]=f2b(a0[e]); w0[4+e]=f2b(a1[e]);
      w1[e]=f2b(a2[e]); w1[4+e]=f2b(a3[e]);
    }
  }
  *(ushort8*)&lds[r*32 + c0]     = w0;
  *(ushort8*)&lds[r*32 + c0 + 8] = w1;
}

// ---------------------------------------------------------------- fused QKV GEMM
__global__ __launch_bounds__(256, 2)
void gemm_qkv(const void* __restrict__ X, const void* __restrict__ Wq,
              const void* __restrict__ Wk, const void* __restrict__ Wv,
              ushort_t* __restrict__ qb, ushort_t* __restrict__ kb,
              ushort_t* __restrict__ vb, const int* __restrict__ flag){
  __shared__ __attribute__((aligned(16))) ushort_t lds_a[128*32];
  __shared__ __attribute__((aligned(16))) ushort_t lds_b[128*32];
  const int isb = flag[0];
  const int tid = threadIdx.x;
  const int wid = tid>>6, lane = tid&63;
  const int lhi = lane>>4, llo = lane&15;
  const int mb = blockIdx.x*128;
  const int ny = blockIdx.y;                    // 0..15 q, 16..19 k, 20..23 v
  const size_t esz = isb ? 2 : 4;
  const char* W = (ny < 16) ? ((const char*)Wq + (size_t)ny*128*DIN*esz)
                : (ny < 20) ? ((const char*)Wk + (size_t)(ny-16)*128*DIN*esz)
                : ((const char*)Wv + (size_t)(ny-20)*128*DIN*esz);
  const int wr = (wid>>1)*64, wc = (wid&1)*64;
  f32x4 acc[4][4];
  #pragma unroll
  for (int i=0;i<4;i++)
    #pragma unroll
    for (int j=0;j<4;j++) acc[i][j] = (f32x4){0.f,0.f,0.f,0.f};

  for (int k0=0; k0<DIN; k0+=32){
    __syncthreads();
    stage_tile((const char*)X + ((size_t)mb*DIN + k0)*esz, DIN, isb, lds_a, tid);
    stage_tile(W + (size_t)k0*esz, DIN, isb, lds_b, tid);
    __syncthreads();
    bf16x8 af[4], bfr[4];
    #pragma unroll
    for (int i=0;i<4;i++) af[i]  = *(const bf16x8*)&lds_a[(wr+i*16+llo)*32 + lhi*8];
    #pragma unroll
    for (int j=0;j<4;j++) bfr[j] = *(const bf16x8*)&lds_b[(wc+j*16+llo)*32 + lhi*8];
    #pragma unroll
    for (int i=0;i<4;i++)
      #pragma unroll
      for (int j=0;j<4;j++)
        acc[i][j] = mfma16(af[i], bfr[j], acc[i][j]);
  }
  #pragma unroll
  for (int i=0;i<4;i++)
    #pragma unroll
    for (int j=0;j<4;j++)
      #pragma unroll
      for (int r=0;r<4;r++){
        int s  = mb + wr + i*16 + lhi*4 + r;
        int nl = wc + j*16 + llo;
        ushort_t val = f2b(acc[i][j][r]);
        if (ny < 16)      qb[(size_t)s*NQ + ny*128 + nl] = val;
        else if (ny < 20) kb[(size_t)(ny-16)*SEQ*DH + (size_t)s*DH + nl] = val;
        else              vb[(size_t)(ny-20)*SEQ*DH + (size_t)s*DH + nl] = val;
      }
}

// ---------------------------------------------------------------- output GEMM
__global__ __launch_bounds__(256, 2)
void gemm_plain(const ushort_t* __restrict__ A, const void* __restrict__ Wo,
                void* __restrict__ out, const int* __restrict__ flag){
  __shared__ __attribute__((aligned(16))) ushort_t lds_a[128*32];
  __shared__ __attribute__((aligned(16))) ushort_t lds_b[128*32];
  const int isb = flag[0];
  const int tid = threadIdx.x;
  const int wid = tid>>6, lane = tid&63;
  const int lhi = lane>>4, llo = lane&15;
  const int mb = blockIdx.x*128;
  const int nb = blockIdx.y*128;
  const size_t esz = isb ? 2 : 4;
  const int wr = (wid>>1)*64, wc = (wid&1)*64;
  f32x4 acc[4][4];
  #pragma unroll
  for (int i=0;i<4;i++)
    #pragma unroll
    for (int j=0;j<4;j++) acc[i][j] = (f32x4){0.f,0.f,0.f,0.f};

  for (int k0=0; k0<NQ; k0+=32){
    __syncthreads();
    stage_tile(A + (size_t)mb*NQ + k0, NQ, 1, lds_a, tid);
    stage_tile((const char*)Wo + ((size_t)nb*NQ + k0)*esz, NQ, isb, lds_b, tid);
    __syncthreads();
    bf16x8 af[4], bfr[4];
    #pragma unroll
    for (int i=0;i<4;i++) af[i]  = *(const bf16x8*)&lds_a[(wr+i*16+llo)*32 + lhi*8];
    #pragma unroll
    for (int j=0;j<4;j++) bfr[j] = *(const bf16x8*)&lds_b[(wc+j*16+llo)*32 + lhi*8];
    #pragma unroll
    for (int i=0;i<4;i++)
      #pragma unroll
      for (int j=0;j<4;j++)
        acc[i][j] = mfma16(af[i], bfr[j], acc[i][j]);
  }
  #pragma unroll
  for (int i=0;i<4;i++)
    #pragma unroll
    for (int j=0;j<4;j++)
      #pragma unroll
      for (int r=0;r<4;r++){
        int s  = mb + wr + i*16 + lhi*4 + r;
        int nl = nb + wc + j*16 + llo;
        float v = acc[i][j][r];
        if (isb) ((ushort_t*)out)[(size_t)s*NQ + nl] = f2b(v);
        else     ((float*)out)[(size_t)s*NQ + nl] = v;
      }
}

// ---------------------------------------------------------------- RoPE (GPT-NeoX pairing j, j+64)
__global__ __launch_bounds__(256)
void rope_kernel(ushort_t* __restrict__ buf, int head_stride, int row_stride, float scale){
  const int idx = blockIdx.x*256 + threadIdx.x;
  const int j = idx & 63;
  const int s = (idx>>6) & (SEQ-1);
  const int h = idx>>17;                        // 64*SEQ = 1<<17 pairs per head
  const size_t a1 = (size_t)h*head_stride + (size_t)s*row_stride + j;
  const size_t a2 = a1 + 64;
  const float inv = __expf((float)j * -0.1439115683f);   // 10000^(-j/64)
  const float ang = (float)s * inv;
  const float c = cosf(ang), sn = sinf(ang);
  const float x1 = b2f(buf[a1]), x2 = b2f(buf[a2]);
  buf[a1] = f2b((x1*c - x2*sn)*scale);
  buf[a2] = f2b((x2*c + x1*sn)*scale);
}

// ---------------------------------------------------------------- V transpose: [kv][S][128] -> [kv][128][S]
__global__ __launch_bounds__(256)
void vtrans(const ushort_t* __restrict__ vb, ushort_t* __restrict__ vt){
  __shared__ __attribute__((aligned(16))) ushort_t tile[64*72];
  const int tid = threadIdx.x;
  const int kv = blockIdx.z, s0 = blockIdx.x*64, d0 = blockIdx.y*64;
  #pragma unroll
  for (int p=0;p<2;p++){
    int lin = p*4096 + tid*16;
    int r = lin>>7, cb = lin&127;               // 128B per 64-elem row chunk
    ushort8 val = *(const ushort8*)&vb[(size_t)kv*SEQ*DH + (size_t)(s0+r)*DH + d0 + (cb>>1)];
    *(ushort8*)&tile[r*72 + (cb>>1)] = val;
  }
  __syncthreads();
  #pragma unroll
  for (int p=0;p<2;p++){
    int lin = p*4096 + tid*16;
    int r = lin>>7, cb = lin&127;
    int c0 = cb>>1;
    ushort8 val;
    #pragma unroll
    for (int e=0;e<8;e++) val[e] = tile[(c0+e)*72 + r];
    *(ushort8*)&vt[(size_t)kv*DH*SEQ + (size_t)(d0+r)*SEQ + s0 + c0] = val;
  }
}

// ---------------------------------------------------------------- Attention
// Block = (qtile of 64 rows, head h). 4 waves x 16 q-rows. Loops kv heads (mean) x causal k-tiles.
// K tile [64][128] and V^T tile [128][64] in LDS, XOR-swizzled (G4) via pre-swizzled global src.
__global__ __launch_bounds__(256, 2)
void attn_kernel(const ushort_t* __restrict__ qb, const ushort_t* __restrict__ kb,
                 const ushort_t* __restrict__ vt, ushort_t* __restrict__ ab){
  __shared__ __attribute__((aligned(16))) ushort_t lds_k[64*128];
  __shared__ __attribute__((aligned(16))) ushort_t lds_v[128*64];
  __shared__ __attribute__((aligned(16))) ushort_t p_lds[4*16*72];
  const int tid = threadIdx.x;
  const int wid = tid>>6, lane = tid&63;
  const int lhi = lane>>4, llo = lane&15;
  const int qt = (int)(gridDim.x - 1 - blockIdx.x);   // heavy tiles first
  const int h = blockIdx.y;
  ushort_t* pl = &p_lds[wid*16*72];

  // Q fragments hoisted (q already RoPE'd and pre-scaled by 1/sqrt(128))
  bf16x8 qf[4];
  {
    const int qrow = qt*64 + wid*16 + llo;
    const ushort_t* qp = qb + (size_t)qrow*NQ + h*DH + lhi*8;
    #pragma unroll
    for (int ks=0;ks<4;ks++) qf[ks] = *(const bf16x8*)(qp + ks*32);
  }
  f32x4 ofin[8];
  #pragma unroll
  for (int dt=0;dt<8;dt++) ofin[dt] = (f32x4){0.f,0.f,0.f,0.f};

  for (int kv=0; kv<NKVH; kv++){
    const ushort_t* kbase = kb + (size_t)kv*SEQ*DH;
    const ushort_t* vbase = vt + (size_t)kv*DH*SEQ;
    f32x4 oacc[8];
    #pragma unroll
    for (int dt=0;dt<8;dt++) oacc[dt] = (f32x4){0.f,0.f,0.f,0.f};
    float mrow[4] = {-1e30f,-1e30f,-1e30f,-1e30f};
    float lrow[4] = {0.f,0.f,0.f,0.f};

    for (int kt=0; kt<=qt; kt++){
      __syncthreads();
      // stage K tile [64][128]: rows 256B, swizzle byte^=(row&7)<<4 on SOURCE (linear LDS dest)
      #pragma unroll
      for (int p=0;p<4;p++){
        int lin = p*4096 + tid*16;
        int r = lin>>8, cb = lin&255;
        int scb = cb ^ ((r&7)<<4);
        gload16(kbase + (size_t)(kt*64 + r)*DH + (scb>>1), (char*)lds_k + p*4096 + (wid<<10));
      }
      // stage V^T tile [128][64]: rows 128B
      #pragma unroll
      for (int p=0;p<4;p++){
        int lin = p*4096 + tid*16;
        int r = lin>>7, cb = lin&127;
        int scb = cb ^ ((r&7)<<4);
        gload16(vbase + (size_t)r*SEQ + kt*64 + (scb>>1), (char*)lds_v + p*4096 + (wid<<10));
      }
      __syncthreads();

      const bool diag = (kt == qt);
      f32x4 sacc[4];
      #pragma unroll
      for (int j=0;j<4;j++) sacc[j] = (f32x4){0.f,0.f,0.f,0.f};
      #pragma unroll
      for (int j=0;j<4;j++){
        if (diag && j > wid) continue;          // fully-masked n-tile
        #pragma unroll
        for (int ks=0;ks<4;ks++){
          int row = j*16 + llo;
          int cb = ks*64 + lhi*16;
          bf16x8 kf = *(const bf16x8*)((const char*)lds_k + row*256 + (cb ^ ((row&7)<<4)));
          sacc[j] = mfma16(qf[ks], kf, sacc[j]);
        }
      }
      // online softmax (rows r -> q-row = wid*16 + lhi*4 + r; cols j*16+llo)
      float al[4];
      float pv[4][4];
      #pragma unroll
      for (int r=0;r<4;r++){
        if (diag){
          int qr = wid*16 + lhi*4 + r;
          #pragma unroll
          for (int j=0;j<4;j++){
            int kc = j*16 + llo;
            if (kc > qr) sacc[j][r] = -1e30f;
          }
        }
        float mt = fmaxf(fmaxf(sacc[0][r], sacc[1][r]), fmaxf(sacc[2][r], sacc[3][r]));
        mt = fmaxf(mt, __shfl_xor(mt, 1));
        mt = fmaxf(mt, __shfl_xor(mt, 2));
        mt = fmaxf(mt, __shfl_xor(mt, 4));
        mt = fmaxf(mt, __shfl_xor(mt, 8));
        float mn = fmaxf(mrow[r], mt);
        al[r] = __expf(mrow[r] - mn);
        mrow[r] = mn;
        float rs = 0.f;
        #pragma unroll
        for (int j=0;j<4;j++){
          float p = __expf(sacc[j][r] - mn);
          pv[j][r] = p;
          rs += p;
        }
        rs += __shfl_xor(rs, 1);
        rs += __shfl_xor(rs, 2);
        rs += __shfl_xor(rs, 4);
        rs += __shfl_xor(rs, 8);
        lrow[r] = lrow[r]*al[r] + rs;
      }
      // P -> per-wave LDS [16][72] (padded: conflict-free), then PV
      #pragma unroll
      for (int j=0;j<4;j++)
        #pragma unroll
        for (int r=0;r<4;r++)
          pl[(lhi*4+r)*72 + j*16 + llo] = f2b(pv[j][r]);
      #pragma unroll
      for (int dt=0;dt<8;dt++){
        oacc[dt][0] *= al[0]; oacc[dt][1] *= al[1];
        oacc[dt][2] *= al[2]; oacc[dt][3] *= al[3];
      }
      #pragma unroll
      for (int ks=0;ks<2;ks++){
        bf16x8 pf = *(const bf16x8*)((const char*)pl + llo*144 + ks*64 + lhi*16);
        #pragma unroll
        for (int dt=0;dt<8;dt++){
          int row = dt*16 + llo;
          int cb = ks*64 + lhi*16;
          bf16x8 vf = *(const bf16x8*)((const char*)lds_v + row*128 + (cb ^ ((row&7)<<4)));
          oacc[dt] = mfma16(pf, vf, oacc[dt]);
        }
      }
    } // kt

    #pragma unroll
    for (int dt=0;dt<8;dt++)
      #pragma unroll
      for (int r=0;r<4;r++)
        ofin[dt][r] += oacc[dt][r] * (0.25f / lrow[r]);   // mean over kv heads
  } // kv

  {
    const int s0 = qt*64 + wid*16 + lhi*4;
    #pragma unroll
    for (int dt=0;dt<8;dt++)
      #pragma unroll
      for (int r=0;r<4;r++)
        ab[(size_t)(s0+r)*NQ + h*DH + dt*16 + llo] = f2b(ofin[dt][r]);
  }
}

// ---------------------------------------------------------------- launch
extern "C" void kernel_launch(void* const* d_in, const int* in_sizes, int n_in,
                              void* d_out, int out_size, void* d_ws, size_t ws_size,
                              hipStream_t stream) {
  const void* x  = d_in[0];
  const void* wq = d_in[1];
  const void* wk = d_in[2];
  const void* wv = d_in[3];
  const void* wo = d_in[4];
  char* ws = (char*)d_ws;
  // workspace layout (bf16): q 8MB | k 2MB | v 2MB | v^T 2MB | attn 8MB | flag
  ushort_t* qbuf = (ushort_t*)(ws);
  ushort_t* kbuf = (ushort_t*)(ws + ((size_t)8<<20));
  ushort_t* vbuf = (ushort_t*)(ws + ((size_t)10<<20));
  ushort_t* vtb  = (ushort_t*)(ws + ((size_t)12<<20));
  ushort_t* ab   = (ushort_t*)(ws + ((size_t)14<<20));
  int* flag      = (int*)(ws + ((size_t)22<<20));

  hipLaunchKernelGGL(detect_bf16, dim3(1), dim3(256), 0, stream, (const ushort_t*)wq, flag);
  hipLaunchKernelGGL(gemm_qkv, dim3(16,24), dim3(256), 0, stream, x, wq, wk, wv, qbuf, kbuf, vbuf, flag);
  hipLaunchKernelGGL(rope_kernel, dim3(8192), dim3(256), 0, stream, qbuf, DH, NQ, QSCALE);      // q: 16 heads
  hipLaunchKernelGGL(rope_kernel, dim3(2048), dim3(256), 0, stream, kbuf, SEQ*DH, DH, 1.0f);    // k: 4 heads
  hipLaunchKernelGGL(vtrans, dim3(32,2,4), dim3(256), 0, stream, vbuf, vtb);
  hipLaunchKernelGGL(attn_kernel, dim3(32,16), dim3(256), 0, stream, qbuf, kbuf, vtb, ab);
  hipLaunchKernelGGL(gemm_plain, dim3(16,16), dim3(256), 0, stream, ab, wo, out_size ? d_out : d_out, flag);
}